// Round 7
// baseline (259.662 us; speedup 1.0000x reference)
//
#include <hip/hip_runtime.h>
#include <hip/hip_bf16.h>
#include <math.h>

#define B_IMG   2
#define N_PROP  2000
#define N_GT    16
#define NPROPS  2016        // N_PROP + N_GT
#define C_FEAT  256
#define H_FEAT  128
#define W_FEAT  128
#define HWF     (H_FEAT*W_FEAT)
#define POOL    7
#define BPI     512
#define NPOSMAX 128
#define NSEL    (B_IMG*BPI)     // 1024
#define K1      (C_FEAT*POOL*POOL)  // 12544
#define K1P     12800           // K1 padded to 16*800
#define HID     1024
#define NHEAD   14
#define SPLITK1 8               // KC = 1600
#define G1_KC   1600

typedef short bf16x8f __attribute__((ext_vector_type(8)));
typedef float f32x4f  __attribute__((ext_vector_type(4)));
typedef short short4v __attribute__((ext_vector_type(4)));

// ---------------------------------------------------------------- threefry
__device__ __forceinline__ void threefry2x32(unsigned k0, unsigned k1,
                                             unsigned& x0, unsigned& x1) {
  unsigned ks[3] = {k0, k1, k0 ^ k1 ^ 0x1BD11BDAu};
  const int R0[4] = {13, 15, 26, 6};
  const int R1[4] = {17, 29, 16, 24};
  x0 += ks[0]; x1 += ks[1];
#pragma unroll
  for (int g = 0; g < 5; g++) {
    const int* rot = (g & 1) ? R1 : R0;
#pragma unroll
    for (int r = 0; r < 4; r++) {
      x0 += x1;
      x1 = (x1 << rot[r]) | (x1 >> (32 - rot[r]));
      x1 ^= x0;
    }
    x0 += ks[(g + 1) % 3];
    x1 += ks[(g + 2) % 3] + (unsigned)(g + 1);
  }
}

// ---------------- mega-prologue: sample+select(2) | transpose(2048) |
//                  castT1(3136) | castT0(256) | pad(512)
// Static LDS = 16640 B (the 64x65 f32 transpose tile) -> 9 blocks/CU.
// The fused sample/select branch is packed to fit UNDER that (16.5 KB):
// no pos_r (re-read rs), mt+lbl packed in bytes, 256-bin counting sort,
// gt_ell read from global at emit.
#define PRE_SAMPLE   2
#define PRE_TRANS    (PRE_SAMPLE + 2048)
#define PRE_CAST1    (PRE_TRANS + 3136)
#define PRE_CAST0    (PRE_CAST1 + 256)
#define PRE_TOTAL    (PRE_CAST0 + 512)

__global__ __launch_bounds__(256) void k_pre(const float* __restrict__ proposals,
                                             const float* __restrict__ gt_boxes,
                                             const int* __restrict__ gt_labels,
                                             const float* __restrict__ features,
                                             const float* __restrict__ w1,
                                             const float* __restrict__ w2,
                                             const float* __restrict__ gt_ell,
                                             __hip_bfloat16* __restrict__ featT,
                                             __hip_bfloat16* __restrict__ W1T,
                                             __hip_bfloat16* __restrict__ W2T,
                                             __hip_bfloat16* __restrict__ Xb,
                                             float* __restrict__ sel_boxes,
                                             int* __restrict__ sel_labels,
                                             float* __restrict__ targets) {
  __shared__ __align__(16) char smem[16640];
  int bid = blockIdx.x;
  int tid = threadIdx.x;
  if (bid < PRE_SAMPLE) {
    // ------- sample + IoU match + FUSED selection (top-512) + encode.
    float* rs           = (float*)smem;                 // [2016]  0..8064
    unsigned char* mtl  = (unsigned char*)(smem + 8064);// [2016]  mt|lbl<<4
    short* pos_i        = (short*)(smem + 10080);       // [2016] ph1/2
    short* glist        = (short*)(smem + 10080);       // ph3 overlay
    int*   Hs           = (int*)(smem + 14112);         // [257] hist/suffix
    int*   curs         = (int*)(smem + 15140);         // [256]
    float* gtb          = (float*)(smem + 16176);       // [64]
    int*   gtl          = (int*)(smem + 16432);         // [16]
    int*   cnt          = (int*)(smem + 16496);
    int b = bid;
    int base = b * NPROPS;
    if (tid == 0) *cnt = 0;
    if (tid < N_GT * 4) gtb[tid] = gt_boxes[b * N_GT * 4 + tid];
    if (tid < N_GT) gtl[tid] = gt_labels[b * N_GT + tid];
    __syncthreads();

    auto emitsel = [&](int slot, int i, int lab) {
      float p0, p1, p2, p3;
      if (i < N_PROP) {
        const float4 v = *(const float4*)(proposals + ((size_t)b * N_PROP + i) * 4);
        p0 = v.x; p1 = v.y; p2 = v.z; p3 = v.w;
      } else {
        const float* g = &gtb[(i - N_PROP) * 4];
        p0 = g[0]; p1 = g[1]; p2 = g[2]; p3 = g[3];
      }
      sel_boxes[slot * 4 + 0] = p0;
      sel_boxes[slot * 4 + 1] = p1;
      sel_boxes[slot * 4 + 2] = p2;
      sel_boxes[slot * 4 + 3] = p3;
      sel_labels[slot] = lab;
      int m = mtl[i] & 15;
      const float* e = gt_ell + ((size_t)b * N_GT + m) * 5;
      float ea = e[0], eb = e[1], ex = e[2], ey = e[3], eth = e[4];
      float w = fmaxf(p2 - p0, 1.0f), h = fmaxf(p3 - p1, 1.0f);
      float cx = 0.5f * (p0 + p2), cy = 0.5f * (p1 + p3);
      float* t = targets + (size_t)slot * 6;
      t[0] = (ex - cx) / w;
      t[1] = (ey - cy) / h;
      t[2] = logf(fmaxf(2.0f * ea, 0.001f) / w);
      t[3] = logf(fmaxf(2.0f * eb, 0.001f) / h);
      t[4] = sinf(2.0f * eth);
      t[5] = cosf(2.0f * eth);
    };

    // ---- phase 1: rand, IoU match, labels, positive collection
    for (int i = tid; i < NPROPS; i += 256) {
      unsigned x0 = 0u, x1 = (unsigned)(base + i);
      threefry2x32(0u, 42u, x0, x1);
      unsigned bits = x0 ^ x1;
      float r = __uint_as_float((bits >> 9) | 0x3F800000u) - 1.0f;
      rs[i] = r;
      float p0, p1, p2, p3;
      if (i < N_PROP) {
        const float4 v = *(const float4*)(proposals + ((size_t)b * N_PROP + i) * 4);
        p0 = v.x; p1 = v.y; p2 = v.z; p3 = v.w;
      } else {
        const float* g = &gtb[(i - N_PROP) * 4];
        p0 = g[0]; p1 = g[1]; p2 = g[2]; p3 = g[3];
      }
      float a2 = (p2 - p0) * (p3 - p1);
      float best = -1.0f; int bg = 0;
#pragma unroll
      for (int g = 0; g < N_GT; g++) {
        float g0 = gtb[g*4], g1 = gtb[g*4+1], g2 = gtb[g*4+2], g3 = gtb[g*4+3];
        float a1 = (g2 - g0) * (g3 - g1);
        float wx = fmaxf(fminf(g2, p2) - fmaxf(g0, p0), 0.0f);
        float wy = fmaxf(fminf(g3, p3) - fmaxf(g1, p1), 0.0f);
        float inter = wx * wy;
        float iou = inter / (a1 + a2 - inter);
        if (iou > best) { best = iou; bg = g; }
      }
      int lab = (best < 0.5f) ? 0 : gtl[bg];
      mtl[i] = (unsigned char)(bg | (lab ? 16 : 0));
      if (lab > 0) {
        int s = atomicAdd(cnt, 1);
        pos_i[s] = (short)i;
      }
    }
    __syncthreads();
    // ---- phase 2: positive ranking; capped positives emit at slot = rank
    int P = *cnt;
    int Pp = (P < NPOSMAX) ? P : NPOSMAX;
    for (int s = tid; s < P; s += 256) {
      int i = pos_i[s]; float ri = rs[i];
      int ch = 0;
      for (int j = 0; j < P; j++) {
        int ij = pos_i[j]; float rj = rs[ij];
        ch += (rj > ri || (rj == ri && ij < i)) ? 1 : 0;
      }
      if (ch < NPOSMAX) {
        int m16 = mtl[i] & 15;
        int lab = gtl[m16];
        emitsel(b * BPI + ch, i, lab);
      }
    }
    __syncthreads();          // done with pos_i before reusing as glist
    // ---- phase 3: negatives via counting sort over 256 bins of r in [0,1)
    for (int idx = tid; idx < 257; idx += 256) Hs[idx] = 0;
    curs[tid] = 0;
    __syncthreads();
    for (int i = tid; i < NPROPS; i += 256)
      if (!(mtl[i] & 16)) {
        int bin = (int)(rs[i] * 256.0f); if (bin > 255) bin = 255;
        atomicAdd(&Hs[bin], 1);
      }
    __syncthreads();
    // in-place inclusive suffix scan: Hs[b] = sum_{b'>=b} hist[b'], Hs[256]=0
    for (int off = 1; off < 256; off <<= 1) {
      int v = Hs[tid] + ((tid + off <= 256) ? Hs[tid + off] : 0);
      __syncthreads();
      Hs[tid] = v;
      __syncthreads();
    }
    // scatter into bin-grouped list (order within bin arbitrary)
    for (int i = tid; i < NPROPS; i += 256)
      if (!(mtl[i] & 16)) {
        int bin = (int)(rs[i] * 256.0f); if (bin > 255) bin = 255;
        int o = atomicAdd(&curs[bin], 1);
        glist[Hs[bin + 1] + o] = (short)i;
      }
    __syncthreads();
    // exact rank within bin; emit selected negatives
    for (int i = tid; i < NPROPS; i += 256)
      if (!(mtl[i] & 16)) {
        int bin = (int)(rs[i] * 256.0f); if (bin > 255) bin = 255;
        int bbase = Hs[bin + 1];
        int cntb = Hs[bin] - bbase;
        float ri = rs[i];
        int wr = 0;
        for (int t = 0; t < cntb; t++) {
          int j = glist[bbase + t];
          if (j != i) {
            float rj = rs[j];
            wr += (rj > ri || (rj == ri && j < i)) ? 1 : 0;
          }
        }
        int slot = Pp + bbase + wr;
        if (slot < BPI) emitsel(b * BPI + slot, i, 0);
      }
  } else if (bid < PRE_TRANS) {
    // ---------------- NCHW -> NHWC bf16, 64x64 tiles
    float (*tile)[65] = (float(*)[65])smem;
    int t = bid - PRE_SAMPLE;
    int b = t >> 10;
    int rem = t & 1023;
    int c0 = (rem >> 8) * 64;
    int s0 = (rem & 255) * 64;
    const float* src = features + (size_t)b * C_FEAT * HWF;
    __hip_bfloat16* dst = featT + (size_t)b * HWF * C_FEAT;
    int hw4 = (tid & 15) * 4, cr = tid >> 4;
#pragma unroll
    for (int p = 0; p < 4; p++) {
      int c = cr + p * 16;
      float4 v = *(const float4*)(src + (size_t)(c0 + c) * HWF + s0 + hw4);
      tile[hw4 + 0][c] = v.x; tile[hw4 + 1][c] = v.y;
      tile[hw4 + 2][c] = v.z; tile[hw4 + 3][c] = v.w;
    }
    __syncthreads();
    int c4 = (tid & 15) * 4, hr = tid >> 4;
#pragma unroll
    for (int p = 0; p < 4; p++) {
      int hw = hr + p * 16;
      __hip_bfloat16 o[4] = {__float2bfloat16(tile[hw][c4]), __float2bfloat16(tile[hw][c4+1]),
                             __float2bfloat16(tile[hw][c4+2]), __float2bfloat16(tile[hw][c4+3])};
      *(short4v*)(dst + (size_t)(s0 + hw) * C_FEAT + c0 + c4) = *(short4v*)o;
    }
  } else if (bid < PRE_CAST1) {
    // ---------------- w1 cast: fp32 [c*49+p][N] -> bf16 [N][p*256+c]
    float (*tile)[65] = (float(*)[65])smem;
    int t = bid - PRE_TRANS;
    int p = t >> 6;
    int rem = t & 63;
    int c0 = (rem & 3) * 64;
    int n0 = (rem >> 2) * 64;
    int n4 = (tid & 15) * 4, ig = tid >> 4;   // 16 row-groups
#pragma unroll
    for (int i = ig; i < 64; i += 16) {
      float4 v = *(const float4*)(w1 + (size_t)((c0 + i) * 49 + p) * HID + n0 + n4);
      tile[i][n4] = v.x; tile[i][n4 + 1] = v.y;
      tile[i][n4 + 2] = v.z; tile[i][n4 + 3] = v.w;
    }
    __syncthreads();
    int c4 = (tid & 15) * 4;
#pragma unroll
    for (int i = ig; i < 64; i += 16) {
      __hip_bfloat16 o[4] = {__float2bfloat16(tile[c4][i]), __float2bfloat16(tile[c4 + 1][i]),
                             __float2bfloat16(tile[c4 + 2][i]), __float2bfloat16(tile[c4 + 3][i])};
      *(short4v*)(W1T + (size_t)(n0 + i) * K1P + p * 256 + c0 + c4) = *(short4v*)o;
    }
  } else if (bid < PRE_CAST0) {
    // ---------------- w2 cast: fp32 [K][N] -> bf16 [N][K], vectorized
    float (*tile)[65] = (float(*)[65])smem;
    int t = bid - PRE_CAST1;
    int c0 = (t & 15) * 64;
    int n0 = (t >> 4) * 64;
    int n4 = (tid & 15) * 4, ig = tid >> 4;
#pragma unroll
    for (int i = ig; i < 64; i += 16) {
      float4 v = *(const float4*)(w2 + (size_t)(c0 + i) * HID + n0 + n4);
      tile[i][n4] = v.x; tile[i][n4 + 1] = v.y;
      tile[i][n4 + 2] = v.z; tile[i][n4 + 3] = v.w;
    }
    __syncthreads();
    int c4 = (tid & 15) * 4;
#pragma unroll
    for (int i = ig; i < 64; i += 16) {
      __hip_bfloat16 o[4] = {__float2bfloat16(tile[c4][i]), __float2bfloat16(tile[c4 + 1][i]),
                             __float2bfloat16(tile[c4 + 2][i]), __float2bfloat16(tile[c4 + 3][i])};
      *(short4v*)(W2T + (size_t)(n0 + i) * HID + c0 + c4) = *(short4v*)o;
    }
  } else {
    // ---------------- zero K-pad cols K1..K1P of Xb / W1T
    int t = bid - PRE_CAST0;        // 0..511
    __hip_bfloat16* buf = (t >> 8) ? W1T : Xb;
    int tt = (t & 255) * 256 + tid;
    int row = tt >> 6;
    int col4 = (tt & 63) << 2;
    short4v z = {0, 0, 0, 0};
    *(short4v*)(buf + (size_t)row * K1P + K1 + col4) = z;
  }
}

// ---------------- roi align (bf16 feat), b128 loads, 32 lanes x 8ch per px
__global__ __launch_bounds__(256) void k_roialign(const __hip_bfloat16* __restrict__ featT,
                                                  const float* __restrict__ sel_boxes,
                                                  __hip_bfloat16* __restrict__ X) {
  int n = blockIdx.x;
  int py = blockIdx.y;
  int t = threadIdx.x;
  int px = t >> 5;            // 0..7 (half-wave granularity)
  int lane32 = t & 31;
  int c = lane32 << 3;        // 8 channels / lane, 16B
  int b = n >> 9;
  const float* bx = sel_boxes + (size_t)n * 4;
  float x1 = bx[0] * 0.125f, y1 = bx[1] * 0.125f;
  float x2 = bx[2] * 0.125f, y2 = bx[3] * 0.125f;
  float bw = fmaxf(x2 - x1, 1.0f) / 7.0f;
  float bh = fmaxf(y2 - y1, 1.0f) / 7.0f;
  if (px >= 7) return;        // upper half of wave 3 idle (1/8)
  const __hip_bfloat16* base = featT + (size_t)b * HWF * C_FEAT;
  int y0A[2]; float lyA[2];
#pragma unroll
  for (int sy = 0; sy < 2; sy++) {
    float off = ((float)(py * 2 + sy) + 0.5f) * 0.5f;
    float ys = fminf(fmaxf(y1 + off * bh, 0.0f), 127.0f);
    int y0 = (int)fminf(fmaxf(floorf(ys), 0.0f), 126.0f);
    y0A[sy] = y0; lyA[sy] = ys - (float)y0;
  }
  float acc[8] = {};
#pragma unroll
  for (int sx = 0; sx < 2; sx++) {
    float off = ((float)(px * 2 + sx) + 0.5f) * 0.5f;
    float xs = fminf(fmaxf(x1 + off * bw, 0.0f), 127.0f);
    int x0 = (int)fminf(fmaxf(floorf(xs), 0.0f), 126.0f);
    float lx = xs - (float)x0;
#pragma unroll
    for (int sy = 0; sy < 2; sy++) {
      int y0 = y0A[sy]; float ly = lyA[sy];
      const __hip_bfloat16* p = base + ((size_t)(y0 * W_FEAT + x0)) * C_FEAT + c;
      bf16x8f s00 = *(const bf16x8f*)p;
      bf16x8f s01 = *(const bf16x8f*)(p + C_FEAT);
      bf16x8f s10 = *(const bf16x8f*)(p + W_FEAT * C_FEAT);
      bf16x8f s11 = *(const bf16x8f*)(p + W_FEAT * C_FEAT + C_FEAT);
      float w00 = (1.0f - ly) * (1.0f - lx), w01 = (1.0f - ly) * lx;
      float w10 = ly * (1.0f - lx), w11 = ly * lx;
#pragma unroll
      for (int q = 0; q < 8; q++) {
        float v00 = __uint_as_float(((unsigned)(unsigned short)s00[q]) << 16);
        float v01 = __uint_as_float(((unsigned)(unsigned short)s01[q]) << 16);
        float v10 = __uint_as_float(((unsigned)(unsigned short)s10[q]) << 16);
        float v11 = __uint_as_float(((unsigned)(unsigned short)s11[q]) << 16);
        acc[q] += v00 * w00 + v01 * w01 + v10 * w10 + v11 * w11;
      }
    }
  }
  __hip_bfloat16 o[8];
#pragma unroll
  for (int q = 0; q < 8; q++) o[q] = __float2bfloat16(acc[q] * 0.25f);
  *(bf16x8f*)&X[(size_t)n * K1P + (size_t)(py * 7 + px) * C_FEAT + c] = *(bf16x8f*)o;
}

// ------------------------------------------------------- global->LDS helper
__device__ __forceinline__ void gld_lds16(const __hip_bfloat16* g, __hip_bfloat16* l) {
  __builtin_amdgcn_global_load_lds(
      (const __attribute__((address_space(1))) void*)g,
      (__attribute__((address_space(3))) void*)l, 16, 0, 0);
}

// ===================== GEMM1: m97-style 128x128, BK=32, split-K=8 =========
// 512 blocks x 256 thr, 16 KB LDS -> multiple blocks/CU co-resident.
__global__ __launch_bounds__(256) void k_gemm1s(const __hip_bfloat16* __restrict__ A,
                                                const __hip_bfloat16* __restrict__ BT,
                                                __hip_bfloat16* __restrict__ Pb) {
  __shared__ __align__(16) __hip_bfloat16 As[128 * 32];
  __shared__ __align__(16) __hip_bfloat16 Bs[128 * 32];
  int lin = blockIdx.x;
  int kz = lin & 7;
  int q  = lin >> 3;
  int n0 = (q & 7) * 128;
  int m0 = (q >> 3) * 128;
  int tid = threadIdx.x;
  int kbeg = kz * G1_KC;
  int srow = tid >> 2;
  int scs  = tid & 3;
  int sg   = scs ^ (srow & 3);
  int scol = sg << 3;
  int wave = tid >> 6, lane = tid & 63;
  int wm = (wave & 1) * 64, wn = (wave >> 1) * 64;
  int lm = lane & 15, quad = lane >> 4;
  int fco = ((quad ^ (lm & 3)) << 3);
  f32x4f acc[4][4] = {};
  for (int k0 = kbeg; k0 < kbeg + G1_KC; k0 += 32) {
    __syncthreads();
#pragma unroll
    for (int r0 = 0; r0 < 128; r0 += 64)
      gld_lds16(A + (size_t)(m0 + r0 + srow) * K1P + k0 + scol, &As[(r0 + srow) * 32 + scs * 8]);
#pragma unroll
    for (int r0 = 0; r0 < 128; r0 += 64)
      gld_lds16(BT + (size_t)(n0 + r0 + srow) * K1P + k0 + scol, &Bs[(r0 + srow) * 32 + scs * 8]);
    __syncthreads();
    bf16x8f af[4], bf[4];
#pragma unroll
    for (int i = 0; i < 4; i++)
      af[i] = *(const bf16x8f*)&As[(wm + i * 16 + lm) * 32 + fco];
#pragma unroll
    for (int j = 0; j < 4; j++)
      bf[j] = *(const bf16x8f*)&Bs[(wn + j * 16 + lm) * 32 + fco];
#pragma unroll
    for (int i = 0; i < 4; i++)
#pragma unroll
      for (int j = 0; j < 4; j++)
        acc[i][j] = __builtin_amdgcn_mfma_f32_16x16x32_bf16(af[i], bf[j], acc[i][j], 0, 0, 0);
  }
  int tileoff = ((m0 >> 7) * 8 + (n0 >> 7)) * 16384;
  __hip_bfloat16* dst = Pb + ((size_t)kz << 20) + tileoff + wave * 4096 + lane * 4;
#pragma unroll
  for (int i = 0; i < 4; i++)
#pragma unroll
    for (int j = 0; j < 4; j++) {
      __hip_bfloat16 o[4] = {__float2bfloat16(acc[i][j][0]), __float2bfloat16(acc[i][j][1]),
                             __float2bfloat16(acc[i][j][2]), __float2bfloat16(acc[i][j][3])};
      *(short4v*)(dst + (i * 4 + j) * 256) = *(short4v*)o;
    }
}

// ---------------- reduce GEMM1 packed partials + bias + relu -> H1b (bf16)
__global__ __launch_bounds__(256) void k_reduce16(const __hip_bfloat16* __restrict__ Pb,
                                                  const float* __restrict__ bias,
                                                  __hip_bfloat16* __restrict__ O) {
  int m4 = blockIdx.x >> 2;
  int n  = (blockIdx.x & 3) * 256 + threadIdx.x;
  int m0i = m4 >> 5, wavem = (m4 >> 4) & 1, i = (m4 >> 2) & 3, quad = m4 & 3;
  int n0i = n >> 7, wn_i = (n >> 6) & 1, j = (n >> 4) & 3, lm = n & 15;
  int wave = wavem + wn_i * 2;
  int elem = (m0i * 8 + n0i) * 16384 + wave * 4096 + (i * 4 + j) * 256 + (quad * 16 + lm) * 4;
  float s0 = 0.0f, s1 = 0.0f, s2 = 0.0f, s3 = 0.0f;
#pragma unroll
  for (int z = 0; z < SPLITK1; z++) {
    short4v v = *(const short4v*)(Pb + ((size_t)z << 20) + elem);
    s0 += __uint_as_float(((unsigned)(unsigned short)v[0]) << 16);
    s1 += __uint_as_float(((unsigned)(unsigned short)v[1]) << 16);
    s2 += __uint_as_float(((unsigned)(unsigned short)v[2]) << 16);
    s3 += __uint_as_float(((unsigned)(unsigned short)v[3]) << 16);
  }
  float bv = bias[n];
  int m = m4 * 4;
  O[(size_t)(m + 0) * HID + n] = __float2bfloat16(fmaxf(s0 + bv, 0.0f));
  O[(size_t)(m + 1) * HID + n] = __float2bfloat16(fmaxf(s1 + bv, 0.0f));
  O[(size_t)(m + 2) * HID + n] = __float2bfloat16(fmaxf(s2 + bv, 0.0f));
  O[(size_t)(m + 3) * HID + n] = __float2bfloat16(fmaxf(s3 + bv, 0.0f));
}

// ===================== GEMM2 + fused head partial + fused loss ============
#define G2_NKT  16
#define G2_ABUF 8192            // 128*64 bf16 elems
#define G2_BUFE 16384           // A + B per buffer (32 KB)
#define H2P     129             // f32 pitch: conflict-free column reads

__global__ __launch_bounds__(512, 1) void k_gemm2h(const __hip_bfloat16* __restrict__ A,
                                                   const __hip_bfloat16* __restrict__ BT,
                                                   const float* __restrict__ b2,
                                                   const float* __restrict__ wc,
                                                   const float* __restrict__ wr,
                                                   float* __restrict__ Ypart,
                                                   const float* __restrict__ bc,
                                                   const float* __restrict__ br,
                                                   const int* __restrict__ sel_labels,
                                                   const float* __restrict__ T,
                                                   float* __restrict__ out,
                                                   int* __restrict__ loss_cnt) {
  __shared__ __align__(16) char smem[3 * G2_BUFE * 2];   // 96 KB, unioned
  __shared__ int lastf;
  __hip_bfloat16* slds = (__hip_bfloat16*)smem;          // K-loop stage bufs
  float* h2 = (float*)smem;                              // [128][H2P] 66 KB
  float* wh = (float*)(smem + 128 * H2P * 4);            // [128][14]   7 KB
  const int m0 = (blockIdx.x >> 3) * 128;
  const int nb = blockIdx.x & 7;
  const int n0 = nb * 128;
  const int tid = threadIdx.x;
  const int wave = tid >> 6, lane = tid & 63;
  const int wm = (wave & 1) * 64, wn = (wave >> 1) * 32;
  const int lm = lane & 15, quad = lane >> 4;

  f32x4f acc[4][2] = {};

  auto stage = [&](int kt, int sb) {
    const int kcol = kt * 64;
    __hip_bfloat16* lb = slds + sb * G2_BUFE;
#pragma unroll
    for (int u = 0; u < 2; ++u) {              // A: 1024 granules / 512 thr
      int idx = tid + u * 512;
      int r = idx >> 3, g = (idx & 7) ^ (r & 7);
      gld_lds16(A + (size_t)(m0 + r) * HID + kcol + g * 8, lb + idx * 8);
    }
#pragma unroll
    for (int u = 0; u < 2; ++u) {              // B: 1024 granules / 512 thr
      int idx = tid + u * 512;
      int r = idx >> 3, g = (idx & 7) ^ (r & 7);
      gld_lds16(BT + (size_t)(n0 + r) * HID + kcol + g * 8, lb + G2_ABUF + idx * 8);
    }
  };

  stage(0, 0);
  stage(1, 1);
  asm volatile("s_waitcnt vmcnt(4)" ::: "memory");   // S(0) resident, S(1) flying
  __builtin_amdgcn_s_barrier();

  int buf = 0;
  for (int kt = 0; kt < G2_NKT; ++kt) {
    int sb = buf + 2; if (sb >= 3) sb -= 3;
    if (kt + 2 < G2_NKT) stage(kt + 2, sb);
    const __hip_bfloat16* Ab = slds + buf * G2_BUFE;
    const __hip_bfloat16* Bb = Ab + G2_ABUF;
    bf16x8f af[4][2], bf[2][2];
#pragma unroll
    for (int i = 0; i < 4; ++i)
#pragma unroll
      for (int s = 0; s < 2; ++s)
        af[i][s] = *(const bf16x8f*)(Ab + (wm + i * 16 + lm) * 64 +
                                     (((s << 2) + quad) ^ (lm & 7)) * 8);
#pragma unroll
    for (int j = 0; j < 2; ++j)
#pragma unroll
      for (int s = 0; s < 2; ++s)
        bf[j][s] = *(const bf16x8f*)(Bb + (wn + j * 16 + lm) * 64 +
                                     (((s << 2) + quad) ^ (lm & 7)) * 8);
    __builtin_amdgcn_s_setprio(1);
#pragma unroll
    for (int s = 0; s < 2; ++s)
#pragma unroll
      for (int i = 0; i < 4; ++i)
#pragma unroll
        for (int j = 0; j < 2; ++j)
          acc[i][j] = __builtin_amdgcn_mfma_f32_16x16x32_bf16(af[i][s], bf[j][s], acc[i][j], 0, 0, 0);
    __builtin_amdgcn_s_setprio(0);
    if (kt < G2_NKT - 1) {
      if (kt < G2_NKT - 2) asm volatile("s_waitcnt vmcnt(4)" ::: "memory");
      else                 asm volatile("s_waitcnt vmcnt(0)" ::: "memory");
      __builtin_amdgcn_s_barrier();
    }
    buf = (buf == 2) ? 0 : buf + 1;
  }
  __syncthreads();      // all ds_reads of stage bufs done before LDS reuse

  // ---- bias + relu -> h2[128][H2P] f32
  float bb[2];
#pragma unroll
  for (int j = 0; j < 2; ++j) bb[j] = b2[n0 + wn + j * 16 + lm];
#pragma unroll
  for (int i = 0; i < 4; ++i)
#pragma unroll
    for (int j = 0; j < 2; ++j) {
      int col = wn + j * 16 + lm;
#pragma unroll
      for (int r = 0; r < 4; ++r) {
        int row = wm + i * 16 + quad * 4 + r;
        h2[row * H2P + col] = fmaxf(acc[i][j][r] + bb[j], 0.0f);
      }
    }
  // ---- stage head weights wh[128 local n][14]
  for (int idx = tid; idx < 128 * 14; idx += 512) {
    int nl = idx / 14, j = idx - nl * 14;
    wh[idx] = (j < 2) ? wc[(size_t)(n0 + nl) * 2 + j]
                      : wr[(size_t)(n0 + nl) * 12 + (j - 2)];
  }
  __syncthreads();
  // ---- head partial: thread (row = tid&127, jg = tid>>7) -> 4 outputs
  {
    int rrow = tid & 127, jg = tid >> 7;       // jg 0..3
    int j0 = jg * 4, jn = (jg == 3) ? 2 : 4;   // 4,4,4,2 -> 14
    float s[4] = {};
#pragma unroll 4
    for (int k = 0; k < 128; ++k) {
      float h = h2[rrow * H2P + k];
      const float* w = wh + k * 14 + j0;
#pragma unroll
      for (int j = 0; j < 4; ++j) s[j] += h * w[j];
    }
    float* yp = Ypart + ((size_t)nb * NSEL + m0 + rrow) * 16 + j0;
    for (int j = 0; j < jn; ++j) yp[j] = s[j];
  }
  // ---------------- last-block loss (64 blocks; &63 poison-safe)
  __syncthreads();
  if (tid == 0) {
    __threadfence();
    int old = atomicAdd(loss_cnt, 1);
    lastf = ((old & 63) == 63) ? 1 : 0;
  }
  __syncthreads();
  if (!lastf) return;
  __threadfence();
  float* sc = (float*)smem;            // 512 floats
  float* sr = sc + 512;                // 512 floats
  float ce_s = 0.0f, rg_s = 0.0f;
#pragma unroll
  for (int half = 0; half < 2; ++half) {
    int n = tid + half * 512;
    float y[14];
#pragma unroll
    for (int j = 0; j < 14; ++j) y[j] = (j < 2) ? bc[j] : br[j - 2];
#pragma unroll
    for (int nb2 = 0; nb2 < 8; ++nb2) {
      const float* p = Ypart + ((size_t)nb2 * NSEL + n) * 16;
      float4 v0 = *(const float4*)(p + 0);
      float4 v1 = *(const float4*)(p + 4);
      float4 v2 = *(const float4*)(p + 8);
      float2 v3 = *(const float2*)(p + 12);
      y[0] += v0.x; y[1] += v0.y; y[2] += v0.z; y[3] += v0.w;
      y[4] += v1.x; y[5] += v1.y; y[6] += v1.z; y[7] += v1.w;
      y[8] += v2.x; y[9] += v2.y; y[10] += v2.z; y[11] += v2.w;
      y[12] += v3.x; y[13] += v3.y;
    }
    int lb = sel_labels[n];
    float mx = fmaxf(y[0], y[1]);
    float lse = mx + logf(expf(y[0] - mx) + expf(y[1] - mx));
    ce_s += lse - (lb ? y[1] : y[0]);
    if (lb > 0) {
      const float beta = 1.0f / 9.0f;
      const float* t = T + (size_t)n * 6;
#pragma unroll
      for (int j = 0; j < 6; j++) {
        float d = fabsf(y[2 + lb * 6 + j] - t[j]);
        rg_s += (d < beta) ? (0.5f * d * d / beta) : (d - 0.5f * beta);
      }
    }
  }
  sc[tid] = ce_s; sr[tid] = rg_s;
  __syncthreads();
  for (int sft = 256; sft > 0; sft >>= 1) {
    if (tid < sft) { sc[tid] += sc[tid + sft]; sr[tid] += sr[tid + sft]; }
    __syncthreads();
  }
  if (tid == 0) {
    out[0] = sc[0] * (1.0f / 1024.0f);
    out[1] = sr[0] * (1.0f / 1024.0f);
  }
}

// ------------------------------------------------------------------ launch
extern "C" void kernel_launch(void* const* d_in, const int* in_sizes, int n_in,
                              void* d_out, int out_size, void* d_ws, size_t ws_size,
                              hipStream_t stream) {
  const float* features  = (const float*)d_in[0];
  const float* proposals = (const float*)d_in[1];
  const float* gt_boxes  = (const float*)d_in[2];
  const int*   gt_labels = (const int*)d_in[3];
  const float* gt_ell    = (const float*)d_in[4];
  const float* w1 = (const float*)d_in[5];
  const float* b1 = (const float*)d_in[6];
  const float* w2 = (const float*)d_in[7];
  const float* b2 = (const float*)d_in[8];
  const float* wc = (const float*)d_in[9];
  const float* bc = (const float*)d_in[10];
  const float* wr = (const float*)d_in[11];
  const float* br = (const float*)d_in[12];
  float* out = (float*)d_out;

  char* ws = (char*)d_ws;
  size_t off = 0;
  auto take = [&](size_t bytes) -> void* {
    void* p = ws + off;
    off = (off + bytes + 255) & ~(size_t)255;
    return p;
  };
  // Pb (8 slabs x 2 MiB used; 16 reserved for layout stability); featT aliases.
  __hip_bfloat16* Pb = (__hip_bfloat16*)take((size_t)16 * (1 << 20) * 2);      // 33.5 MB
  __hip_bfloat16* featT = Pb;                                                  // alias
  __hip_bfloat16* Xb  = (__hip_bfloat16*)take((size_t)NSEL * K1P * 2);         // 26.2 MB
  __hip_bfloat16* W1T = (__hip_bfloat16*)take((size_t)HID * K1P * 2);          // 26.2 MB
  __hip_bfloat16* W2T = (__hip_bfloat16*)take((size_t)HID * HID * 2);          // 2.1 MB
  __hip_bfloat16* H1b = (__hip_bfloat16*)take((size_t)NSEL * HID * 2);         // 2.1 MB
  float* Ypart     = (float*)take((size_t)8 * NSEL * 16 * 4);                  // 524 KB
  float* sel_boxes = (float*)take((size_t)NSEL * 4 * 4);
  int*   sel_lab   = (int*)take((size_t)NSEL * 4);
  float* targets   = (float*)take((size_t)NSEL * 6 * 4);
  int*   loss_cnt  = (int*)take(256);

  k_pre<<<PRE_TOTAL, 256, 0, stream>>>(proposals, gt_boxes, gt_labels, features,
                                       w1, w2, gt_ell, featT, W1T, W2T, Xb,
                                       sel_boxes, sel_lab, targets);
  k_roialign<<<dim3(NSEL, POOL), 256, 0, stream>>>(featT, sel_boxes, Xb);

  // GEMM1: m97-style 128x128 tile, BK=32, split-K=8, 512 blocks x 256 thr
  k_gemm1s<<<512, 256, 0, stream>>>(Xb, W1T, Pb);
  k_reduce16<<<1024, 256, 0, stream>>>(Pb, b1, H1b);
  // GEMM2 + head partial + fused last-block loss: 64 blocks, 512 thr
  k_gemm2h<<<64, 512, 0, stream>>>(H1b, W2T, b2, wc, wr, Ypart,
                                   bc, br, sel_lab, targets, out, loss_cnt);
}

// Round 8
// 240.427 us; speedup vs baseline: 1.0800x; 1.0800x over previous
//
#include <hip/hip_runtime.h>
#include <hip/hip_bf16.h>
#include <math.h>

#define B_IMG   2
#define N_PROP  2000
#define N_GT    16
#define NPROPS  2016        // N_PROP + N_GT
#define C_FEAT  256
#define H_FEAT  128
#define W_FEAT  128
#define HWF     (H_FEAT*W_FEAT)
#define POOL    7
#define BPI     512
#define NPOSMAX 128
#define NSEL    (B_IMG*BPI)     // 1024
#define K1      (C_FEAT*POOL*POOL)  // 12544
#define K1P     12800           // K1 padded to 16*800
#define HID     1024
#define NHEAD   14
#define SPLITK1 8               // KC = 1600
#define G1_KC   1600

typedef short bf16x8f __attribute__((ext_vector_type(8)));
typedef float f32x4f  __attribute__((ext_vector_type(4)));
typedef short short4v __attribute__((ext_vector_type(4)));

// ---------------------------------------------------------------- threefry
__device__ __forceinline__ void threefry2x32(unsigned k0, unsigned k1,
                                             unsigned& x0, unsigned& x1) {
  unsigned ks[3] = {k0, k1, k0 ^ k1 ^ 0x1BD11BDAu};
  const int R0[4] = {13, 15, 26, 6};
  const int R1[4] = {17, 29, 16, 24};
  x0 += ks[0]; x1 += ks[1];
#pragma unroll
  for (int g = 0; g < 5; g++) {
    const int* rot = (g & 1) ? R1 : R0;
#pragma unroll
    for (int r = 0; r < 4; r++) {
      x0 += x1;
      x1 = (x1 << rot[r]) | (x1 >> (32 - rot[r]));
      x1 ^= x0;
    }
    x0 += ks[(g + 1) % 3];
    x1 += ks[(g + 2) % 3] + (unsigned)(g + 1);
  }
}

// ---------------- mega-prologue: sample(2) | transpose(2048) |
//                  castT1(3136) | castT0(256) | pad(512)
// Static LDS = 16640 B (the 64x65 f32 transpose tile) -> ~8 blocks/CU.
// Sample branch does ONLY prio/plab/matches (12.4 KB LDS); selection runs
// in the wide parallel k_select kernel (round-4 structure: the fused
// single-block select was a 25-55 us serial tail — r6/r7 post-mortem).
#define PRE_SAMPLE   2
#define PRE_TRANS    (PRE_SAMPLE + 2048)
#define PRE_CAST1    (PRE_TRANS + 3136)
#define PRE_CAST0    (PRE_CAST1 + 256)
#define PRE_TOTAL    (PRE_CAST0 + 512)

__global__ __launch_bounds__(256) void k_pre(const float* __restrict__ proposals,
                                             const float* __restrict__ gt_boxes,
                                             const int* __restrict__ gt_labels,
                                             const float* __restrict__ features,
                                             const float* __restrict__ w1,
                                             const float* __restrict__ w2,
                                             float* __restrict__ prio,
                                             int* __restrict__ plab,
                                             int* __restrict__ matches,
                                             __hip_bfloat16* __restrict__ featT,
                                             __hip_bfloat16* __restrict__ W1T,
                                             __hip_bfloat16* __restrict__ W2T,
                                             __hip_bfloat16* __restrict__ Xb) {
  __shared__ __align__(16) char smem[16640];
  int bid = blockIdx.x;
  int tid = threadIdx.x;
  if (bid < PRE_SAMPLE) {
    // ---------------- sample: rand + IoU match + positive-rank priorities
    float* rs    = (float*)smem;              // [2016]           0..8064
    short* pos_i = (short*)(smem + 8064);     // [2016]           8064..12096
    float* gtb   = (float*)(smem + 12096);    // [64]
    int*   gtl   = (int*)(smem + 12352);      // [16]
    int*   cnt   = (int*)(smem + 12416);
    int b = bid;
    int base = b * NPROPS;
    if (tid == 0) *cnt = 0;
    if (tid < N_GT * 4) gtb[tid] = gt_boxes[b * N_GT * 4 + tid];
    if (tid < N_GT) gtl[tid] = gt_labels[b * N_GT + tid];
    __syncthreads();
    for (int i = tid; i < NPROPS; i += 256) {
      unsigned x0 = 0u, x1 = (unsigned)(base + i);
      threefry2x32(0u, 42u, x0, x1);
      unsigned bits = x0 ^ x1;
      float r = __uint_as_float((bits >> 9) | 0x3F800000u) - 1.0f;
      rs[i] = r;
      float p0, p1, p2, p3;
      if (i < N_PROP) {
        const float4 v = *(const float4*)(proposals + ((size_t)b * N_PROP + i) * 4);
        p0 = v.x; p1 = v.y; p2 = v.z; p3 = v.w;
      } else {
        const float* g = &gtb[(i - N_PROP) * 4];
        p0 = g[0]; p1 = g[1]; p2 = g[2]; p3 = g[3];
      }
      float a2 = (p2 - p0) * (p3 - p1);
      float best = -1.0f; int bg = 0;
#pragma unroll
      for (int g = 0; g < N_GT; g++) {
        float g0 = gtb[g*4], g1 = gtb[g*4+1], g2 = gtb[g*4+2], g3 = gtb[g*4+3];
        float a1 = (g2 - g0) * (g3 - g1);
        float wx = fmaxf(fminf(g2, p2) - fmaxf(g0, p0), 0.0f);
        float wy = fmaxf(fminf(g3, p3) - fmaxf(g1, p1), 0.0f);
        float inter = wx * wy;
        float iou = inter / (a1 + a2 - inter);
        if (iou > best) { best = iou; bg = g; }
      }
      matches[base + i] = bg;
      int lab = (best < 0.5f) ? 0 : gtl[bg];
      plab[base + i] = lab;
      if (lab > 0) {
        int s = atomicAdd(cnt, 1);
        pos_i[s] = (short)i;
      }
    }
    __syncthreads();
    // positive ranking (deferred write: readers see unmodified rs)
    int P = *cnt;
    int ii[8]; float nv[8]; int nloc = 0;
    for (int s = tid; s < P; s += 256) {
      int i = pos_i[s]; float ri = rs[i];
      int ch = 0;
      for (int j = 0; j < P; j++) {
        int ij = pos_i[j]; float rj = rs[ij];
        ch += (rj > ri || (rj == ri && ij < i)) ? 1 : 0;
      }
      ii[nloc] = i;
      nv[nloc++] = (ch < NPOSMAX) ? (ri + 2.0f) : -1000000000.0f;
    }
    __syncthreads();
    for (int k2 = 0; k2 < nloc; k2++) rs[ii[k2]] = nv[k2];
    __syncthreads();
    for (int i = tid; i < NPROPS; i += 256) prio[base + i] = rs[i];
  } else if (bid < PRE_TRANS) {
    // ---------------- NCHW -> NHWC bf16, 64x64 tiles
    float (*tile)[65] = (float(*)[65])smem;
    int t = bid - PRE_SAMPLE;
    int b = t >> 10;
    int rem = t & 1023;
    int c0 = (rem >> 8) * 64;
    int s0 = (rem & 255) * 64;
    const float* src = features + (size_t)b * C_FEAT * HWF;
    __hip_bfloat16* dst = featT + (size_t)b * HWF * C_FEAT;
    int hw4 = (tid & 15) * 4, cr = tid >> 4;
#pragma unroll
    for (int p = 0; p < 4; p++) {
      int c = cr + p * 16;
      float4 v = *(const float4*)(src + (size_t)(c0 + c) * HWF + s0 + hw4);
      tile[hw4 + 0][c] = v.x; tile[hw4 + 1][c] = v.y;
      tile[hw4 + 2][c] = v.z; tile[hw4 + 3][c] = v.w;
    }
    __syncthreads();
    int c4 = (tid & 15) * 4, hr = tid >> 4;
#pragma unroll
    for (int p = 0; p < 4; p++) {
      int hw = hr + p * 16;
      __hip_bfloat16 o[4] = {__float2bfloat16(tile[hw][c4]), __float2bfloat16(tile[hw][c4+1]),
                             __float2bfloat16(tile[hw][c4+2]), __float2bfloat16(tile[hw][c4+3])};
      *(short4v*)(dst + (size_t)(s0 + hw) * C_FEAT + c0 + c4) = *(short4v*)o;
    }
  } else if (bid < PRE_CAST1) {
    // ---------------- w1 cast: fp32 [c*49+p][N] -> bf16 [N][p*256+c]
    float (*tile)[65] = (float(*)[65])smem;
    int t = bid - PRE_TRANS;
    int p = t >> 6;
    int rem = t & 63;
    int c0 = (rem & 3) * 64;
    int n0 = (rem >> 2) * 64;
    int n4 = (tid & 15) * 4, ig = tid >> 4;   // 16 row-groups
#pragma unroll
    for (int i = ig; i < 64; i += 16) {
      float4 v = *(const float4*)(w1 + (size_t)((c0 + i) * 49 + p) * HID + n0 + n4);
      tile[i][n4] = v.x; tile[i][n4 + 1] = v.y;
      tile[i][n4 + 2] = v.z; tile[i][n4 + 3] = v.w;
    }
    __syncthreads();
    int c4 = (tid & 15) * 4;
#pragma unroll
    for (int i = ig; i < 64; i += 16) {
      __hip_bfloat16 o[4] = {__float2bfloat16(tile[c4][i]), __float2bfloat16(tile[c4 + 1][i]),
                             __float2bfloat16(tile[c4 + 2][i]), __float2bfloat16(tile[c4 + 3][i])};
      *(short4v*)(W1T + (size_t)(n0 + i) * K1P + p * 256 + c0 + c4) = *(short4v*)o;
    }
  } else if (bid < PRE_CAST0) {
    // ---------------- w2 cast: fp32 [K][N] -> bf16 [N][K], vectorized
    float (*tile)[65] = (float(*)[65])smem;
    int t = bid - PRE_CAST1;
    int c0 = (t & 15) * 64;
    int n0 = (t >> 4) * 64;
    int n4 = (tid & 15) * 4, ig = tid >> 4;
#pragma unroll
    for (int i = ig; i < 64; i += 16) {
      float4 v = *(const float4*)(w2 + (size_t)(c0 + i) * HID + n0 + n4);
      tile[i][n4] = v.x; tile[i][n4 + 1] = v.y;
      tile[i][n4 + 2] = v.z; tile[i][n4 + 3] = v.w;
    }
    __syncthreads();
    int c4 = (tid & 15) * 4;
#pragma unroll
    for (int i = ig; i < 64; i += 16) {
      __hip_bfloat16 o[4] = {__float2bfloat16(tile[c4][i]), __float2bfloat16(tile[c4 + 1][i]),
                             __float2bfloat16(tile[c4 + 2][i]), __float2bfloat16(tile[c4 + 3][i])};
      *(short4v*)(W2T + (size_t)(n0 + i) * HID + c0 + c4) = *(short4v*)o;
    }
  } else {
    // ---------------- zero K-pad cols K1..K1P of Xb / W1T
    int t = bid - PRE_CAST0;        // 0..511
    __hip_bfloat16* buf = (t >> 8) ? W1T : Xb;
    int tt = (t & 255) * 256 + tid;
    int row = tt >> 6;
    int col4 = (tt & 63) << 2;
    short4v z = {0, 0, 0, 0};
    *(short4v*)(buf + (size_t)row * K1P + K1 + col4) = z;
  }
}

// ------------------------------------------------- select + gather + encode
// (round-4 verified structure: one wave ranks one candidate, fully parallel)
__global__ __launch_bounds__(256) void k_select(const float* __restrict__ prio,
    const float* __restrict__ proposals, const float* __restrict__ gt_boxes,
    const int* __restrict__ matches, const int* __restrict__ plab,
    const float* __restrict__ gt_ell,
    float* __restrict__ sel_boxes, int* __restrict__ sel_labels,
    float* __restrict__ targets) {
  int tid = threadIdx.x;
  int wave = tid >> 6, lane = tid & 63;
  int b = blockIdx.y;
  int base = b * NPROPS;
  int i = blockIdx.x * 4 + wave;
  float pi = prio[base + i];
  int rank = 0;
  for (int j = lane; j < NPROPS; j += 64) {
    float pj = prio[base + j];
    rank += (pj > pi || (pj == pi && j < i)) ? 1 : 0;
  }
#pragma unroll
  for (int off = 32; off > 0; off >>= 1) rank += __shfl_down(rank, off);
  if (lane != 0 || rank >= BPI) return;
  int slot = b * BPI + rank;
  float p0, p1, p2, p3;
  if (i < N_PROP) {
    const float* p = proposals + ((size_t)b * N_PROP + i) * 4;
    p0 = p[0]; p1 = p[1]; p2 = p[2]; p3 = p[3];
  } else {
    const float* p = gt_boxes + ((size_t)b * N_GT + (i - N_PROP)) * 4;
    p0 = p[0]; p1 = p[1]; p2 = p[2]; p3 = p[3];
  }
  sel_boxes[slot * 4 + 0] = p0;
  sel_boxes[slot * 4 + 1] = p1;
  sel_boxes[slot * 4 + 2] = p2;
  sel_boxes[slot * 4 + 3] = p3;
  int lb = plab[base + i];
  sel_labels[slot] = lb;
  int m = matches[base + i];
  const float* e = gt_ell + ((size_t)b * N_GT + m) * 5;
  float ea = e[0], eb = e[1], ex = e[2], ey = e[3], eth = e[4];
  float w = fmaxf(p2 - p0, 1.0f), h = fmaxf(p3 - p1, 1.0f);
  float cx = 0.5f * (p0 + p2), cy = 0.5f * (p1 + p3);
  float* t = targets + (size_t)slot * 6;
  t[0] = (ex - cx) / w;
  t[1] = (ey - cy) / h;
  t[2] = logf(fmaxf(2.0f * ea, 0.001f) / w);
  t[3] = logf(fmaxf(2.0f * eb, 0.001f) / h);
  t[4] = sinf(2.0f * eth);
  t[5] = cosf(2.0f * eth);
}

// ---------------- roi align (bf16 feat), b128 loads, 32 lanes x 8ch per px
__global__ __launch_bounds__(256) void k_roialign(const __hip_bfloat16* __restrict__ featT,
                                                  const float* __restrict__ sel_boxes,
                                                  __hip_bfloat16* __restrict__ X) {
  int n = blockIdx.x;
  int py = blockIdx.y;
  int t = threadIdx.x;
  int px = t >> 5;            // 0..7 (half-wave granularity)
  int lane32 = t & 31;
  int c = lane32 << 3;        // 8 channels / lane, 16B
  int b = n >> 9;
  const float* bx = sel_boxes + (size_t)n * 4;
  float x1 = bx[0] * 0.125f, y1 = bx[1] * 0.125f;
  float x2 = bx[2] * 0.125f, y2 = bx[3] * 0.125f;
  float bw = fmaxf(x2 - x1, 1.0f) / 7.0f;
  float bh = fmaxf(y2 - y1, 1.0f) / 7.0f;
  if (px >= 7) return;        // upper half of wave 3 idle (1/8)
  const __hip_bfloat16* base = featT + (size_t)b * HWF * C_FEAT;
  int y0A[2]; float lyA[2];
#pragma unroll
  for (int sy = 0; sy < 2; sy++) {
    float off = ((float)(py * 2 + sy) + 0.5f) * 0.5f;
    float ys = fminf(fmaxf(y1 + off * bh, 0.0f), 127.0f);
    int y0 = (int)fminf(fmaxf(floorf(ys), 0.0f), 126.0f);
    y0A[sy] = y0; lyA[sy] = ys - (float)y0;
  }
  float acc[8] = {};
#pragma unroll
  for (int sx = 0; sx < 2; sx++) {
    float off = ((float)(px * 2 + sx) + 0.5f) * 0.5f;
    float xs = fminf(fmaxf(x1 + off * bw, 0.0f), 127.0f);
    int x0 = (int)fminf(fmaxf(floorf(xs), 0.0f), 126.0f);
    float lx = xs - (float)x0;
#pragma unroll
    for (int sy = 0; sy < 2; sy++) {
      int y0 = y0A[sy]; float ly = lyA[sy];
      const __hip_bfloat16* p = base + ((size_t)(y0 * W_FEAT + x0)) * C_FEAT + c;
      bf16x8f s00 = *(const bf16x8f*)p;
      bf16x8f s01 = *(const bf16x8f*)(p + C_FEAT);
      bf16x8f s10 = *(const bf16x8f*)(p + W_FEAT * C_FEAT);
      bf16x8f s11 = *(const bf16x8f*)(p + W_FEAT * C_FEAT + C_FEAT);
      float w00 = (1.0f - ly) * (1.0f - lx), w01 = (1.0f - ly) * lx;
      float w10 = ly * (1.0f - lx), w11 = ly * lx;
#pragma unroll
      for (int q = 0; q < 8; q++) {
        float v00 = __uint_as_float(((unsigned)(unsigned short)s00[q]) << 16);
        float v01 = __uint_as_float(((unsigned)(unsigned short)s01[q]) << 16);
        float v10 = __uint_as_float(((unsigned)(unsigned short)s10[q]) << 16);
        float v11 = __uint_as_float(((unsigned)(unsigned short)s11[q]) << 16);
        acc[q] += v00 * w00 + v01 * w01 + v10 * w10 + v11 * w11;
      }
    }
  }
  __hip_bfloat16 o[8];
#pragma unroll
  for (int q = 0; q < 8; q++) o[q] = __float2bfloat16(acc[q] * 0.25f);
  *(bf16x8f*)&X[(size_t)n * K1P + (size_t)(py * 7 + px) * C_FEAT + c] = *(bf16x8f*)o;
}

// ------------------------------------------------------- global->LDS helper
__device__ __forceinline__ void gld_lds16(const __hip_bfloat16* g, __hip_bfloat16* l) {
  __builtin_amdgcn_global_load_lds(
      (const __attribute__((address_space(1))) void*)g,
      (__attribute__((address_space(3))) void*)l, 16, 0, 0);
}

// ===================== GEMM1: m97-style 128x128, BK=32, split-K=8 =========
// 512 blocks x 256 thr, 16 KB LDS -> multiple blocks/CU co-resident.
__global__ __launch_bounds__(256) void k_gemm1s(const __hip_bfloat16* __restrict__ A,
                                                const __hip_bfloat16* __restrict__ BT,
                                                __hip_bfloat16* __restrict__ Pb) {
  __shared__ __align__(16) __hip_bfloat16 As[128 * 32];
  __shared__ __align__(16) __hip_bfloat16 Bs[128 * 32];
  int lin = blockIdx.x;
  int kz = lin & 7;
  int q  = lin >> 3;
  int n0 = (q & 7) * 128;
  int m0 = (q >> 3) * 128;
  int tid = threadIdx.x;
  int kbeg = kz * G1_KC;
  int srow = tid >> 2;
  int scs  = tid & 3;
  int sg   = scs ^ (srow & 3);
  int scol = sg << 3;
  int wave = tid >> 6, lane = tid & 63;
  int wm = (wave & 1) * 64, wn = (wave >> 1) * 64;
  int lm = lane & 15, quad = lane >> 4;
  int fco = ((quad ^ (lm & 3)) << 3);
  f32x4f acc[4][4] = {};
  for (int k0 = kbeg; k0 < kbeg + G1_KC; k0 += 32) {
    __syncthreads();
#pragma unroll
    for (int r0 = 0; r0 < 128; r0 += 64)
      gld_lds16(A + (size_t)(m0 + r0 + srow) * K1P + k0 + scol, &As[(r0 + srow) * 32 + scs * 8]);
#pragma unroll
    for (int r0 = 0; r0 < 128; r0 += 64)
      gld_lds16(BT + (size_t)(n0 + r0 + srow) * K1P + k0 + scol, &Bs[(r0 + srow) * 32 + scs * 8]);
    __syncthreads();
    bf16x8f af[4], bf[4];
#pragma unroll
    for (int i = 0; i < 4; i++)
      af[i] = *(const bf16x8f*)&As[(wm + i * 16 + lm) * 32 + fco];
#pragma unroll
    for (int j = 0; j < 4; j++)
      bf[j] = *(const bf16x8f*)&Bs[(wn + j * 16 + lm) * 32 + fco];
#pragma unroll
    for (int i = 0; i < 4; i++)
#pragma unroll
      for (int j = 0; j < 4; j++)
        acc[i][j] = __builtin_amdgcn_mfma_f32_16x16x32_bf16(af[i], bf[j], acc[i][j], 0, 0, 0);
  }
  int tileoff = ((m0 >> 7) * 8 + (n0 >> 7)) * 16384;
  __hip_bfloat16* dst = Pb + ((size_t)kz << 20) + tileoff + wave * 4096 + lane * 4;
#pragma unroll
  for (int i = 0; i < 4; i++)
#pragma unroll
    for (int j = 0; j < 4; j++) {
      __hip_bfloat16 o[4] = {__float2bfloat16(acc[i][j][0]), __float2bfloat16(acc[i][j][1]),
                             __float2bfloat16(acc[i][j][2]), __float2bfloat16(acc[i][j][3])};
      *(short4v*)(dst + (i * 4 + j) * 256) = *(short4v*)o;
    }
}

// ---------------- reduce GEMM1 packed partials + bias + relu -> H1b (bf16)
__global__ __launch_bounds__(256) void k_reduce16(const __hip_bfloat16* __restrict__ Pb,
                                                  const float* __restrict__ bias,
                                                  __hip_bfloat16* __restrict__ O) {
  int m4 = blockIdx.x >> 2;
  int n  = (blockIdx.x & 3) * 256 + threadIdx.x;
  int m0i = m4 >> 5, wavem = (m4 >> 4) & 1, i = (m4 >> 2) & 3, quad = m4 & 3;
  int n0i = n >> 7, wn_i = (n >> 6) & 1, j = (n >> 4) & 3, lm = n & 15;
  int wave = wavem + wn_i * 2;
  int elem = (m0i * 8 + n0i) * 16384 + wave * 4096 + (i * 4 + j) * 256 + (quad * 16 + lm) * 4;
  float s0 = 0.0f, s1 = 0.0f, s2 = 0.0f, s3 = 0.0f;
#pragma unroll
  for (int z = 0; z < SPLITK1; z++) {
    short4v v = *(const short4v*)(Pb + ((size_t)z << 20) + elem);
    s0 += __uint_as_float(((unsigned)(unsigned short)v[0]) << 16);
    s1 += __uint_as_float(((unsigned)(unsigned short)v[1]) << 16);
    s2 += __uint_as_float(((unsigned)(unsigned short)v[2]) << 16);
    s3 += __uint_as_float(((unsigned)(unsigned short)v[3]) << 16);
  }
  float bv = bias[n];
  int m = m4 * 4;
  O[(size_t)(m + 0) * HID + n] = __float2bfloat16(fmaxf(s0 + bv, 0.0f));
  O[(size_t)(m + 1) * HID + n] = __float2bfloat16(fmaxf(s1 + bv, 0.0f));
  O[(size_t)(m + 2) * HID + n] = __float2bfloat16(fmaxf(s2 + bv, 0.0f));
  O[(size_t)(m + 3) * HID + n] = __float2bfloat16(fmaxf(s3 + bv, 0.0f));
}

// ===================== GEMM2 + fused head partial + fused loss ============
#define G2_NKT  16
#define G2_ABUF 8192            // 128*64 bf16 elems
#define G2_BUFE 16384           // A + B per buffer (32 KB)
#define H2P     129             // f32 pitch: conflict-free column reads

__global__ __launch_bounds__(512, 1) void k_gemm2h(const __hip_bfloat16* __restrict__ A,
                                                   const __hip_bfloat16* __restrict__ BT,
                                                   const float* __restrict__ b2,
                                                   const float* __restrict__ wc,
                                                   const float* __restrict__ wr,
                                                   float* __restrict__ Ypart,
                                                   const float* __restrict__ bc,
                                                   const float* __restrict__ br,
                                                   const int* __restrict__ sel_labels,
                                                   const float* __restrict__ T,
                                                   float* __restrict__ out,
                                                   int* __restrict__ loss_cnt) {
  __shared__ __align__(16) char smem[3 * G2_BUFE * 2];   // 96 KB, unioned
  __shared__ int lastf;
  __hip_bfloat16* slds = (__hip_bfloat16*)smem;          // K-loop stage bufs
  float* h2 = (float*)smem;                              // [128][H2P] 66 KB
  float* wh = (float*)(smem + 128 * H2P * 4);            // [128][14]   7 KB
  const int m0 = (blockIdx.x >> 3) * 128;
  const int nb = blockIdx.x & 7;
  const int n0 = nb * 128;
  const int tid = threadIdx.x;
  const int wave = tid >> 6, lane = tid & 63;
  const int wm = (wave & 1) * 64, wn = (wave >> 1) * 32;
  const int lm = lane & 15, quad = lane >> 4;

  f32x4f acc[4][2] = {};

  auto stage = [&](int kt, int sb) {
    const int kcol = kt * 64;
    __hip_bfloat16* lb = slds + sb * G2_BUFE;
#pragma unroll
    for (int u = 0; u < 2; ++u) {              // A: 1024 granules / 512 thr
      int idx = tid + u * 512;
      int r = idx >> 3, g = (idx & 7) ^ (r & 7);
      gld_lds16(A + (size_t)(m0 + r) * HID + kcol + g * 8, lb + idx * 8);
    }
#pragma unroll
    for (int u = 0; u < 2; ++u) {              // B: 1024 granules / 512 thr
      int idx = tid + u * 512;
      int r = idx >> 3, g = (idx & 7) ^ (r & 7);
      gld_lds16(BT + (size_t)(n0 + r) * HID + kcol + g * 8, lb + G2_ABUF + idx * 8);
    }
  };

  stage(0, 0);
  stage(1, 1);
  asm volatile("s_waitcnt vmcnt(4)" ::: "memory");   // S(0) resident, S(1) flying
  __builtin_amdgcn_s_barrier();

  int buf = 0;
  for (int kt = 0; kt < G2_NKT; ++kt) {
    int sb = buf + 2; if (sb >= 3) sb -= 3;
    if (kt + 2 < G2_NKT) stage(kt + 2, sb);
    const __hip_bfloat16* Ab = slds + buf * G2_BUFE;
    const __hip_bfloat16* Bb = Ab + G2_ABUF;
    bf16x8f af[4][2], bf[2][2];
#pragma unroll
    for (int i = 0; i < 4; ++i)
#pragma unroll
      for (int s = 0; s < 2; ++s)
        af[i][s] = *(const bf16x8f*)(Ab + (wm + i * 16 + lm) * 64 +
                                     (((s << 2) + quad) ^ (lm & 7)) * 8);
#pragma unroll
    for (int j = 0; j < 2; ++j)
#pragma unroll
      for (int s = 0; s < 2; ++s)
        bf[j][s] = *(const bf16x8f*)(Bb + (wn + j * 16 + lm) * 64 +
                                     (((s << 2) + quad) ^ (lm & 7)) * 8);
    __builtin_amdgcn_s_setprio(1);
#pragma unroll
    for (int s = 0; s < 2; ++s)
#pragma unroll
      for (int i = 0; i < 4; ++i)
#pragma unroll
        for (int j = 0; j < 2; ++j)
          acc[i][j] = __builtin_amdgcn_mfma_f32_16x16x32_bf16(af[i][s], bf[j][s], acc[i][j], 0, 0, 0);
    __builtin_amdgcn_s_setprio(0);
    if (kt < G2_NKT - 1) {
      if (kt < G2_NKT - 2) asm volatile("s_waitcnt vmcnt(4)" ::: "memory");
      else                 asm volatile("s_waitcnt vmcnt(0)" ::: "memory");
      __builtin_amdgcn_s_barrier();
    }
    buf = (buf == 2) ? 0 : buf + 1;
  }
  __syncthreads();      // all ds_reads of stage bufs done before LDS reuse

  // ---- bias + relu -> h2[128][H2P] f32
  float bb[2];
#pragma unroll
  for (int j = 0; j < 2; ++j) bb[j] = b2[n0 + wn + j * 16 + lm];
#pragma unroll
  for (int i = 0; i < 4; ++i)
#pragma unroll
    for (int j = 0; j < 2; ++j) {
      int col = wn + j * 16 + lm;
#pragma unroll
      for (int r = 0; r < 4; ++r) {
        int row = wm + i * 16 + quad * 4 + r;
        h2[row * H2P + col] = fmaxf(acc[i][j][r] + bb[j], 0.0f);
      }
    }
  // ---- stage head weights wh[128 local n][14]
  for (int idx = tid; idx < 128 * 14; idx += 512) {
    int nl = idx / 14, j = idx - nl * 14;
    wh[idx] = (j < 2) ? wc[(size_t)(n0 + nl) * 2 + j]
                      : wr[(size_t)(n0 + nl) * 12 + (j - 2)];
  }
  __syncthreads();
  // ---- head partial: thread (row = tid&127, jg = tid>>7) -> 4 outputs
  {
    int rrow = tid & 127, jg = tid >> 7;       // jg 0..3
    int j0 = jg * 4, jn = (jg == 3) ? 2 : 4;   // 4,4,4,2 -> 14
    float s[4] = {};
#pragma unroll 4
    for (int k = 0; k < 128; ++k) {
      float h = h2[rrow * H2P + k];
      const float* w = wh + k * 14 + j0;
#pragma unroll
      for (int j = 0; j < 4; ++j) s[j] += h * w[j];
    }
    float* yp = Ypart + ((size_t)nb * NSEL + m0 + rrow) * 16 + j0;
    for (int j = 0; j < jn; ++j) yp[j] = s[j];
  }
  // ---------------- last-block loss (64 blocks; &63 poison-safe)
  __syncthreads();
  if (tid == 0) {
    __threadfence();
    int old = atomicAdd(loss_cnt, 1);
    lastf = ((old & 63) == 63) ? 1 : 0;
  }
  __syncthreads();
  if (!lastf) return;
  __threadfence();
  float* sc = (float*)smem;            // 512 floats
  float* sr = sc + 512;                // 512 floats
  float ce_s = 0.0f, rg_s = 0.0f;
#pragma unroll
  for (int half = 0; half < 2; ++half) {
    int n = tid + half * 512;
    float y[14];
#pragma unroll
    for (int j = 0; j < 14; ++j) y[j] = (j < 2) ? bc[j] : br[j - 2];
#pragma unroll
    for (int nb2 = 0; nb2 < 8; ++nb2) {
      const float* p = Ypart + ((size_t)nb2 * NSEL + n) * 16;
      float4 v0 = *(const float4*)(p + 0);
      float4 v1 = *(const float4*)(p + 4);
      float4 v2 = *(const float4*)(p + 8);
      float2 v3 = *(const float2*)(p + 12);
      y[0] += v0.x; y[1] += v0.y; y[2] += v0.z; y[3] += v0.w;
      y[4] += v1.x; y[5] += v1.y; y[6] += v1.z; y[7] += v1.w;
      y[8] += v2.x; y[9] += v2.y; y[10] += v2.z; y[11] += v2.w;
      y[12] += v3.x; y[13] += v3.y;
    }
    int lb = sel_labels[n];
    float mx = fmaxf(y[0], y[1]);
    float lse = mx + logf(expf(y[0] - mx) + expf(y[1] - mx));
    ce_s += lse - (lb ? y[1] : y[0]);
    if (lb > 0) {
      const float beta = 1.0f / 9.0f;
      const float* t = T + (size_t)n * 6;
#pragma unroll
      for (int j = 0; j < 6; j++) {
        float d = fabsf(y[2 + lb * 6 + j] - t[j]);
        rg_s += (d < beta) ? (0.5f * d * d / beta) : (d - 0.5f * beta);
      }
    }
  }
  sc[tid] = ce_s; sr[tid] = rg_s;
  __syncthreads();
  for (int sft = 256; sft > 0; sft >>= 1) {
    if (tid < sft) { sc[tid] += sc[tid + sft]; sr[tid] += sr[tid + sft]; }
    __syncthreads();
  }
  if (tid == 0) {
    out[0] = sc[0] * (1.0f / 1024.0f);
    out[1] = sr[0] * (1.0f / 1024.0f);
  }
}

// ------------------------------------------------------------------ launch
extern "C" void kernel_launch(void* const* d_in, const int* in_sizes, int n_in,
                              void* d_out, int out_size, void* d_ws, size_t ws_size,
                              hipStream_t stream) {
  const float* features  = (const float*)d_in[0];
  const float* proposals = (const float*)d_in[1];
  const float* gt_boxes  = (const float*)d_in[2];
  const int*   gt_labels = (const int*)d_in[3];
  const float* gt_ell    = (const float*)d_in[4];
  const float* w1 = (const float*)d_in[5];
  const float* b1 = (const float*)d_in[6];
  const float* w2 = (const float*)d_in[7];
  const float* b2 = (const float*)d_in[8];
  const float* wc = (const float*)d_in[9];
  const float* bc = (const float*)d_in[10];
  const float* wr = (const float*)d_in[11];
  const float* br = (const float*)d_in[12];
  float* out = (float*)d_out;

  char* ws = (char*)d_ws;
  size_t off = 0;
  auto take = [&](size_t bytes) -> void* {
    void* p = ws + off;
    off = (off + bytes + 255) & ~(size_t)255;
    return p;
  };
  // Pb (8 slabs x 2 MiB used; 16 reserved for layout stability); featT aliases.
  __hip_bfloat16* Pb = (__hip_bfloat16*)take((size_t)16 * (1 << 20) * 2);      // 33.5 MB
  __hip_bfloat16* featT = Pb;                                                  // alias
  __hip_bfloat16* Xb  = (__hip_bfloat16*)take((size_t)NSEL * K1P * 2);         // 26.2 MB
  __hip_bfloat16* W1T = (__hip_bfloat16*)take((size_t)HID * K1P * 2);          // 26.2 MB
  __hip_bfloat16* W2T = (__hip_bfloat16*)take((size_t)HID * HID * 2);          // 2.1 MB
  __hip_bfloat16* H1b = (__hip_bfloat16*)take((size_t)NSEL * HID * 2);         // 2.1 MB
  float* Ypart     = (float*)take((size_t)8 * NSEL * 16 * 4);                  // 524 KB
  int*   matches   = (int*)take((size_t)B_IMG * NPROPS * 4);
  int*   plab      = (int*)take((size_t)B_IMG * NPROPS * 4);
  float* prio      = (float*)take((size_t)B_IMG * NPROPS * 4);
  float* sel_boxes = (float*)take((size_t)NSEL * 4 * 4);
  int*   sel_lab   = (int*)take((size_t)NSEL * 4);
  float* targets   = (float*)take((size_t)NSEL * 6 * 4);
  int*   loss_cnt  = (int*)take(256);

  k_pre<<<PRE_TOTAL, 256, 0, stream>>>(proposals, gt_boxes, gt_labels, features,
                                       w1, w2, prio, plab, matches,
                                       featT, W1T, W2T, Xb);
  k_select<<<dim3(NPROPS / 4, B_IMG), 256, 0, stream>>>(prio, proposals, gt_boxes,
                                                        matches, plab, gt_ell,
                                                        sel_boxes, sel_lab, targets);
  k_roialign<<<dim3(NSEL, POOL), 256, 0, stream>>>(featT, sel_boxes, Xb);

  // GEMM1: m97-style 128x128 tile, BK=32, split-K=8, 512 blocks x 256 thr
  k_gemm1s<<<512, 256, 0, stream>>>(Xb, W1T, Pb);
  k_reduce16<<<1024, 256, 0, stream>>>(Pb, b1, H1b);
  // GEMM2 + head partial + fused last-block loss: 64 blocks, 512 thr
  k_gemm2h<<<64, 512, 0, stream>>>(H1b, W2T, b2, wc, wr, Ypart,
                                   bc, br, sel_lab, targets, out, loss_cnt);
}